// Round 1
// baseline (156.514 us; speedup 1.0000x reference)
//
#include <hip/hip_runtime.h>
#include <math.h>

// Problem constants (from reference setup_inputs)
#define B_ 256
#define V_ 50
#define C_ 32
#define E_ 128
#define L_ (V_ * C_)     // 1600 flattened codes per patient
#define NW 16            // waves per block (1024 threads)

// One block per patient. Wave-per-row gathers: 64 lanes x float2 = 512B row.
__global__ __launch_bounds__(1024, 1) void clinical_embedding_kernel(
    const float* __restrict__ W,      // [VOCAB, E] fp32
    const int*   __restrict__ codes,  // [B, V, C] (int32 from harness)
    const int*   __restrict__ nvis,   // [B]
    float*       __restrict__ out)    // [B, V, E] fp32
{
    const int b    = blockIdx.x;
    const int tid  = threadIdx.x;
    const int wave = tid >> 6;
    const int lane = tid & 63;

    const int nv = nvis[b];
    const int* cf = codes + b * L_;
    float* ob = out + (size_t)b * V_ * E_;

    // 1) zero the top padding rows [0, V-nv)
    const int padN = (V_ - nv) * E_;
    for (int idx = tid; idx < padN; idx += 1024) ob[idx] = 0.0f;

    // 2) single-embedding rows: bag i in [0, nv-1) -> output row V-nv+i
    for (int i = wave; i < nv - 1; i += NW) {
        const int code = cf[i];
        float2 v = ((const float2*)(W + (size_t)code * E_))[lane];
        float ss = v.x * v.x + v.y * v.y;
        #pragma unroll
        for (int off = 32; off > 0; off >>= 1) ss += __shfl_xor(ss, off, 64);
        const float sc = fminf(1.0f, 1.0f / fmaxf(sqrtf(ss), 1e-12f));
        ((float2*)(ob + (size_t)(V_ - nv + i) * E_))[lane] =
            make_float2(v.x * sc, v.y * sc);
    }

    // 3) last bag: sum of renormalized g[j] for j in [nv-1, nv*C)
    float accx = 0.0f, accy = 0.0f;
    const int jend = nv * C_;
    #pragma unroll 4
    for (int j = nv - 1 + wave; j < jend; j += NW) {
        const int code = cf[j];
        float2 v = ((const float2*)(W + (size_t)code * E_))[lane];
        float ss = v.x * v.x + v.y * v.y;
        #pragma unroll
        for (int off = 32; off > 0; off >>= 1) ss += __shfl_xor(ss, off, 64);
        const float sc = fminf(1.0f, 1.0f / fmaxf(sqrtf(ss), 1e-12f));
        accx += v.x * sc;
        accy += v.y * sc;
    }

    // cross-wave reduction (16 waves x 64 lanes x float2 = 8 KB LDS)
    __shared__ float sredx[NW][64];
    __shared__ float sredy[NW][64];
    sredx[wave][lane] = accx;
    sredy[wave][lane] = accy;
    __syncthreads();
    if (wave == 0) {
        float sx = 0.0f, sy = 0.0f;
        #pragma unroll
        for (int w = 0; w < NW; w++) { sx += sredx[w][lane]; sy += sredy[w][lane]; }
        ((float2*)(ob + (size_t)(V_ - 1) * E_))[lane] = make_float2(sx, sy);
    }
}

extern "C" void kernel_launch(void* const* d_in, const int* in_sizes, int n_in,
                              void* d_out, int out_size, void* d_ws, size_t ws_size,
                              hipStream_t stream) {
    const float* W     = (const float*)d_in[0];
    const int*   codes = (const int*)d_in[1];
    const int*   nvis  = (const int*)d_in[2];
    float*       out   = (float*)d_out;

    clinical_embedding_kernel<<<B_, 1024, 0, stream>>>(W, codes, nvis, out);
}

// Round 2
// 119.560 us; speedup vs baseline: 1.3091x; 1.3091x over previous
//
#include <hip/hip_runtime.h>
#include <math.h>

// Problem constants (from reference setup_inputs)
#define B_     256
#define V_     50
#define C_     32
#define E_     128
#define VOCAB_ 100000
#define L_     (V_ * C_)   // 1600 flattened codes per patient
#define SPLIT  8           // blocks per patient for the last-bag sum

// K1: scales[r] = min(1, 1/max(||W[r]||, 1e-12)). One wave per vocab row,
// streaming coalesced reads — perfectly balanced across the chip.
__global__ __launch_bounds__(1024) void scales_kernel(
    const float* __restrict__ W, float* __restrict__ scales)
{
    const int wave = threadIdx.x >> 6;
    const int lane = threadIdx.x & 63;
    const int r = blockIdx.x * 16 + wave;
    if (r >= VOCAB_) return;
    float2 v = ((const float2*)(W + (size_t)r * E_))[lane];
    float ss = v.x * v.x + v.y * v.y;
    #pragma unroll
    for (int off = 32; off > 0; off >>= 1) ss += __shfl_xor(ss, off, 64);
    if (lane == 0)
        scales[r] = fminf(1.0f, 1.0f / fmaxf(sqrtf(ss), 1e-12f));
}

// K2: single-embedding rows. One wave per candidate (b, i) bag, i < nv-1.
// out row = (V - nv + i); pure copy-scale, no reduction chain.
__global__ __launch_bounds__(256) void singles_kernel(
    const float* __restrict__ W, const float* __restrict__ scales,
    const int* __restrict__ codes, const int* __restrict__ nvis,
    float* __restrict__ out)
{
    const int wg   = blockIdx.x * 4 + (threadIdx.x >> 6);
    const int lane = threadIdx.x & 63;
    const int b = wg / (V_ - 1);
    const int i = wg % (V_ - 1);
    if (b >= B_) return;
    const int nv = nvis[b];
    if (i >= nv - 1) return;
    const int code = codes[b * L_ + i];
    const float sc = scales[code];
    float2 v = ((const float2*)(W + (size_t)code * E_))[lane];
    ((float2*)(out + ((size_t)b * V_ + (V_ - nv + i)) * E_))[lane] =
        make_float2(v.x * sc, v.y * sc);
}

// K3: last-bag sums. SPLIT blocks per patient, 4 waves per block; each wave
// accumulates scale[code]*row over its strided slice (short dep chain ->
// high MLP), block-reduces in LDS, then atomicAdds onto the zeroed out row.
__global__ __launch_bounds__(256) void bags_kernel(
    const float* __restrict__ W, const float* __restrict__ scales,
    const int* __restrict__ codes, const int* __restrict__ nvis,
    float* __restrict__ out)
{
    const int b    = blockIdx.x / SPLIT;
    const int s    = blockIdx.x % SPLIT;
    const int wave = threadIdx.x >> 6;
    const int lane = threadIdx.x & 63;

    const int nv  = nvis[b];
    const int j0  = nv - 1;
    const int j1  = nv * C_;
    const int chunk = (j1 - j0 + SPLIT - 1) / SPLIT;
    const int a0 = j0 + s * chunk;
    const int a1 = min(a0 + chunk, j1);
    const int* cf = codes + b * L_;

    float ax = 0.0f, ay = 0.0f;
    #pragma unroll 4
    for (int j = a0 + wave; j < a1; j += 4) {
        const int code = cf[j];
        const float sc = scales[code];
        float2 v = ((const float2*)(W + (size_t)code * E_))[lane];
        ax += v.x * sc;
        ay += v.y * sc;
    }

    __shared__ float sx[4][64], sy[4][64];
    sx[wave][lane] = ax;
    sy[wave][lane] = ay;
    __syncthreads();
    if (wave == 0) {
        const float fx = sx[0][lane] + sx[1][lane] + sx[2][lane] + sx[3][lane];
        const float fy = sy[0][lane] + sy[1][lane] + sy[2][lane] + sy[3][lane];
        float* dst = out + ((size_t)b * V_ + (V_ - 1)) * E_;
        atomicAdd(&dst[2 * lane],     fx);
        atomicAdd(&dst[2 * lane + 1], fy);
    }
}

extern "C" void kernel_launch(void* const* d_in, const int* in_sizes, int n_in,
                              void* d_out, int out_size, void* d_ws, size_t ws_size,
                              hipStream_t stream) {
    const float* W     = (const float*)d_in[0];
    const int*   codes = (const int*)d_in[1];
    const int*   nvis  = (const int*)d_in[2];
    float*       out   = (float*)d_out;
    float*       scales = (float*)d_ws;   // VOCAB_ * 4 B = 400 KB scratch

    // zero output: pad rows stay 0, last rows are atomicAdd bases
    hipMemsetAsync(out, 0, (size_t)out_size * sizeof(float), stream);

    scales_kernel<<<(VOCAB_ + 15) / 16, 1024, 0, stream>>>(W, scales);
    singles_kernel<<<(B_ * (V_ - 1) + 3) / 4, 256, 0, stream>>>(W, scales, codes, nvis, out);
    bags_kernel<<<B_ * SPLIT, 256, 0, stream>>>(W, scales, codes, nvis, out);
}

// Round 3
// 116.861 us; speedup vs baseline: 1.3393x; 1.0231x over previous
//
#include <hip/hip_runtime.h>
#include <math.h>

// Problem constants (from reference setup_inputs)
#define B_     256
#define V_     50
#define C_     32
#define E_     128
#define VOCAB_ 100000
#define L_     (V_ * C_)   // 1600 flattened codes per patient
#define SPLIT  8           // blocks per patient for the last-bag sum

// K1: scales[r] = min(1, 1/max(||W[r]||, 1e-12)). One wave per vocab row,
// streaming coalesced 512B reads — perfectly balanced, also warms L3 with W.
__global__ __launch_bounds__(1024) void scales_kernel(
    const float* __restrict__ W, float* __restrict__ scales)
{
    const int wave = threadIdx.x >> 6;
    const int lane = threadIdx.x & 63;
    const int r = blockIdx.x * 16 + wave;
    if (r >= VOCAB_) return;
    float2 v = ((const float2*)(W + (size_t)r * E_))[lane];
    float ss = v.x * v.x + v.y * v.y;
    #pragma unroll
    for (int off = 32; off > 0; off >>= 1) ss += __shfl_xor(ss, off, 64);
    if (lane == 0)
        scales[r] = fminf(1.0f, 1.0f / fmaxf(sqrtf(ss), 1e-12f));
}

// K2: one wave per (b, i), i in [0, V). Covers ALL output rows except the
// additive part of the bag row:
//   i <  nv-1        -> single row: out[V-nv+i] = scale * W[code]
//   nv-1 <= i < V-1  -> pad row:    out[i-(nv-1)] = 0
//   i == V-1         -> zero the bag row (atomicAdd base for K3)
__global__ __launch_bounds__(256) void singles_kernel(
    const float* __restrict__ W, const float* __restrict__ scales,
    const int* __restrict__ codes, const int* __restrict__ nvis,
    float* __restrict__ out)
{
    const int wg   = blockIdx.x * 4 + (threadIdx.x >> 6);
    const int lane = threadIdx.x & 63;
    const int b = wg / V_;
    const int i = wg % V_;
    if (b >= B_) return;
    const int nv = nvis[b];
    float* ob = out + (size_t)b * V_ * E_;

    if (i == V_ - 1) {
        ((float2*)(ob + (size_t)(V_ - 1) * E_))[lane] = make_float2(0.0f, 0.0f);
    } else if (i < nv - 1) {
        const int code = codes[b * L_ + i];
        const float sc = scales[code];
        float2 v = ((const float2*)(W + (size_t)code * E_))[lane];
        ((float2*)(ob + (size_t)(V_ - nv + i) * E_))[lane] =
            make_float2(v.x * sc, v.y * sc);
    } else {
        // pad row index i-(nv-1) in [0, V-nv)
        ((float2*)(ob + (size_t)(i - (nv - 1)) * E_))[lane] =
            make_float2(0.0f, 0.0f);
    }
}

// K3: last-bag sums. SPLIT blocks per patient, 4 waves per block; each wave
// accumulates scale[code]*row over its strided slice (unroll 8 -> 8
// independent 512B gathers in flight), block-reduces in LDS, then atomicAdds
// onto the bag row zeroed by K2 (stream order guarantees visibility).
__global__ __launch_bounds__(256) void bags_kernel(
    const float* __restrict__ W, const float* __restrict__ scales,
    const int* __restrict__ codes, const int* __restrict__ nvis,
    float* __restrict__ out)
{
    const int b    = blockIdx.x / SPLIT;
    const int s    = blockIdx.x % SPLIT;
    const int wave = threadIdx.x >> 6;
    const int lane = threadIdx.x & 63;

    const int nv  = nvis[b];
    const int j0  = nv - 1;
    const int j1  = nv * C_;
    const int chunk = (j1 - j0 + SPLIT - 1) / SPLIT;
    const int a0 = j0 + s * chunk;
    const int a1 = min(a0 + chunk, j1);
    const int* cf = codes + b * L_;

    float ax = 0.0f, ay = 0.0f;
    #pragma unroll 8
    for (int j = a0 + wave; j < a1; j += 4) {
        const int code = cf[j];
        const float sc = scales[code];
        float2 v = ((const float2*)(W + (size_t)code * E_))[lane];
        ax += v.x * sc;
        ay += v.y * sc;
    }

    __shared__ float sx[4][64], sy[4][64];
    sx[wave][lane] = ax;
    sy[wave][lane] = ay;
    __syncthreads();
    if (wave == 0) {
        const float fx = sx[0][lane] + sx[1][lane] + sx[2][lane] + sx[3][lane];
        const float fy = sy[0][lane] + sy[1][lane] + sy[2][lane] + sy[3][lane];
        float* dst = out + ((size_t)b * V_ + (V_ - 1)) * E_;
        atomicAdd(&dst[2 * lane],     fx);
        atomicAdd(&dst[2 * lane + 1], fy);
    }
}

extern "C" void kernel_launch(void* const* d_in, const int* in_sizes, int n_in,
                              void* d_out, int out_size, void* d_ws, size_t ws_size,
                              hipStream_t stream) {
    const float* W     = (const float*)d_in[0];
    const int*   codes = (const int*)d_in[1];
    const int*   nvis  = (const int*)d_in[2];
    float*       out   = (float*)d_out;
    float*       scales = (float*)d_ws;   // VOCAB_ * 4 B = 400 KB scratch

    scales_kernel<<<(VOCAB_ + 15) / 16, 1024, 0, stream>>>(W, scales);
    singles_kernel<<<(B_ * V_ + 3) / 4, 256, 0, stream>>>(W, scales, codes, nvis, out);
    bags_kernel<<<B_ * SPLIT, 256, 0, stream>>>(W, scales, codes, nvis, out);
}

// Round 4
// 109.046 us; speedup vs baseline: 1.4353x; 1.0717x over previous
//
#include <hip/hip_runtime.h>
#include <math.h>

// Problem constants (from reference setup_inputs)
#define B_     256
#define V_     50
#define C_     32
#define E_     128
#define VOCAB_ 100000
#define L_     (V_ * C_)      // 1600 flattened codes per patient
#define SPLIT  8              // blocks per patient for the last-bag sum
#define NWB    (SPLIT * 4)    // bag waves per patient (32) -> chunk <= 50

// K1: scales[r] = min(1, 1/max(||W[r]||, 1e-12)).
// float4 half-wave: each wave computes 2 rows (2 x 32 lanes x 16B).
// 3125 blocks x 32 rows = exactly 100000 rows, no bounds check needed.
__global__ __launch_bounds__(1024) void scales_kernel(
    const float* __restrict__ W, float* __restrict__ scales)
{
    const int wave = threadIdx.x >> 6;
    const int lane = threadIdx.x & 63;
    const int half = lane >> 5;
    const int hl   = lane & 31;
    const int r = blockIdx.x * 32 + wave * 2 + half;
    float4 v = ((const float4*)(W + (size_t)r * E_))[hl];
    float ss = v.x * v.x + v.y * v.y + v.z * v.z + v.w * v.w;
    #pragma unroll
    for (int m = 1; m <= 16; m <<= 1) ss += __shfl_xor(ss, m, 64);  // within half-wave
    if (hl == 0)
        scales[r] = fminf(1.0f, 1.0f / fmaxf(sqrtf(ss), 1e-12f));
}

// K2: one HALF-WAVE per (b, i), i in [0, V). float4 = full row per half-wave.
//   i <  nv-1        -> single row: out[V-nv+i] = scale * W[code]
//   nv-1 <= i < V-1  -> pad row:    out[i-(nv-1)] = 0
//   i == V-1         -> zero the bag row (atomicAdd base for K3)
// 12800 half-waves -> exactly 1600 blocks of 256.
__global__ __launch_bounds__(256) void singles_kernel(
    const float* __restrict__ W, const float* __restrict__ scales,
    const int* __restrict__ codes, const int* __restrict__ nvis,
    float* __restrict__ out)
{
    const int hwid = (blockIdx.x * 256 + threadIdx.x) >> 5;
    const int hl   = threadIdx.x & 31;
    const int b = hwid / V_;
    const int i = hwid % V_;
    const int nv = nvis[b];
    float* ob = out + (size_t)b * V_ * E_;

    if (i == V_ - 1) {
        ((float4*)(ob + (size_t)(V_ - 1) * E_))[hl] = make_float4(0.f, 0.f, 0.f, 0.f);
    } else if (i < nv - 1) {
        const int code = codes[b * L_ + i];
        const float sc = scales[code];
        float4 v = ((const float4*)(W + (size_t)code * E_))[hl];
        ((float4*)(ob + (size_t)(V_ - nv + i) * E_))[hl] =
            make_float4(v.x * sc, v.y * sc, v.z * sc, v.w * sc);
    } else {
        ((float4*)(ob + (size_t)(i - (nv - 1)) * E_))[hl] =
            make_float4(0.f, 0.f, 0.f, 0.f);
    }
}

// K3: last-bag sums. SPLIT blocks x 4 waves per patient, contiguous chunks
// (chunk <= 50 codes per wave). Phase 1: lane t loads code t + scale t
// coalesced (ONE code load + ONE scale gather per wave). Phase 2: inner loop
// is shfl-broadcast + float4 row load (2 rows per load via half-waves) + fma
// — the only in-loop memory op is the row gather, unroll 4 => 8 rows in
// flight per wave. Then half-combine, LDS block-reduce, atomicAdd onto the
// bag row zeroed by K2.
__global__ __launch_bounds__(256) void bags_kernel(
    const float* __restrict__ W, const float* __restrict__ scales,
    const int* __restrict__ codes, const int* __restrict__ nvis,
    float* __restrict__ out)
{
    const int b    = blockIdx.x / SPLIT;
    const int s    = blockIdx.x % SPLIT;
    const int wave = threadIdx.x >> 6;
    const int lane = threadIdx.x & 63;
    const int half = lane >> 5;
    const int hl   = lane & 31;

    const int nv    = nvis[b];
    const int j0    = nv - 1;
    const int j1    = nv * C_;
    const int total = j1 - j0;                       // 32..1569
    const int chunk = (total + NWB - 1) / NWB;       // <= 50
    const int wid   = s * 4 + wave;
    const int a0    = j0 + wid * chunk;
    const int n     = min(a0 + chunk, j1) - a0;      // may be <= 0
    const int* cf   = codes + b * L_;

    // Phase 1: batched, coalesced code + scale fetch (lane t -> code a0+t)
    int   cl = 0;
    float sl = 0.0f;
    if (lane < n) {
        cl = cf[a0 + lane];
        sl = scales[cl];
    }

    // Phase 2: row gathers. half 0 -> code t, half 1 -> code t+1.
    float ax = 0.f, ay = 0.f, az = 0.f, aw = 0.f;
    #pragma unroll 4
    for (int t = 0; t < n; t += 2) {
        const int   tt   = t + half;                 // tt==n lane holds sc=0
        const int   code = __shfl(cl, tt, 64);
        const float sc   = __shfl(sl, tt, 64);
        float4 v = ((const float4*)(W + (size_t)code * E_))[hl];
        ax += v.x * sc; ay += v.y * sc; az += v.z * sc; aw += v.w * sc;
    }

    // combine the two halves (same dims in both)
    ax += __shfl_xor(ax, 32, 64);
    ay += __shfl_xor(ay, 32, 64);
    az += __shfl_xor(az, 32, 64);
    aw += __shfl_xor(aw, 32, 64);

    __shared__ float sx[4][32], sy[4][32], sz[4][32], sw[4][32];
    if (half == 0) {
        sx[wave][hl] = ax; sy[wave][hl] = ay; sz[wave][hl] = az; sw[wave][hl] = aw;
    }
    __syncthreads();
    if (threadIdx.x < 32) {
        const float fx = sx[0][hl] + sx[1][hl] + sx[2][hl] + sx[3][hl];
        const float fy = sy[0][hl] + sy[1][hl] + sy[2][hl] + sy[3][hl];
        const float fz = sz[0][hl] + sz[1][hl] + sz[2][hl] + sz[3][hl];
        const float fw = sw[0][hl] + sw[1][hl] + sw[2][hl] + sw[3][hl];
        float* dst = out + ((size_t)b * V_ + (V_ - 1)) * E_ + 4 * hl;
        atomicAdd(&dst[0], fx);
        atomicAdd(&dst[1], fy);
        atomicAdd(&dst[2], fz);
        atomicAdd(&dst[3], fw);
    }
}

extern "C" void kernel_launch(void* const* d_in, const int* in_sizes, int n_in,
                              void* d_out, int out_size, void* d_ws, size_t ws_size,
                              hipStream_t stream) {
    const float* W      = (const float*)d_in[0];
    const int*   codes  = (const int*)d_in[1];
    const int*   nvis   = (const int*)d_in[2];
    float*       out    = (float*)d_out;
    float*       scales = (float*)d_ws;   // VOCAB_ * 4 B = 400 KB scratch

    scales_kernel <<<VOCAB_ / 32, 1024, 0, stream>>>(W, scales);
    singles_kernel<<<B_ * V_ / 8, 256, 0, stream>>>(W, scales, codes, nvis, out);
    bags_kernel   <<<B_ * SPLIT, 256, 0, stream>>>(W, scales, codes, nvis, out);
}